// Round 7
// baseline (238.225 us; speedup 1.0000x reference)
//
#include <hip/hip_runtime.h>
#include <hip/hip_bf16.h>

using bf16 = __hip_bfloat16;
using bf16x8 = __attribute__((ext_vector_type(8))) __bf16;
using f32x4 = __attribute__((ext_vector_type(4))) float;
using f32x16 = __attribute__((ext_vector_type(16))) float;

typedef const __attribute__((address_space(1))) void* gas_ptr;
typedef __attribute__((address_space(3))) void* las_ptr;
#define LOAD_LDS16(g, l) \
    __builtin_amdgcn_global_load_lds((gas_ptr)(const void*)(g), (las_ptr)(void*)(l), 16, 0, 0)

#define LOG_DIM 11
#define BDIM 2048
#define NFEAT 2048
#define BATCH 16384

__device__ __forceinline__ void cvt_chunk(const float* __restrict__ x,
                                          bf16* __restrict__ x_bf, int chunk, int tid) {
    #pragma unroll
    for (int it = 0; it < 16; ++it) {
        size_t i = ((size_t)chunk * 16 + it) * 2048 + tid * 8;
        float4 v0 = *(const float4*)(x + i);
        float4 v1 = *(const float4*)(x + i + 4);
        union { bf16 h[8]; int4 v; } u;
        u.h[0] = __float2bfloat16(v0.x); u.h[1] = __float2bfloat16(v0.y);
        u.h[2] = __float2bfloat16(v0.z); u.h[3] = __float2bfloat16(v0.w);
        u.h[4] = __float2bfloat16(v1.x); u.h[5] = __float2bfloat16(v1.y);
        u.h[6] = __float2bfloat16(v1.z); u.h[7] = __float2bfloat16(v1.w);
        *(int4*)(x_bf + i) = u.v;
    }
}

// ---------------------------------------------------------------------------
// prep1: butterfly_wout [0,2048) || transpose_cvt [2048,6144) || cvt [6144,6400)
// ---------------------------------------------------------------------------
__global__ __launch_bounds__(256) void prep1(const float* __restrict__ w_out,
                                             const float* __restrict__ a_pad,
                                             const float* __restrict__ b_pad,
                                             const float* __restrict__ w_in,
                                             bf16* __restrict__ woutb,
                                             bf16* __restrict__ wint,
                                             const float* __restrict__ x,
                                             bf16* __restrict__ x_bf) {
    __shared__ float v[BDIM];
    __shared__ float tile[32][33];
    const int t = threadIdx.x;
    if (blockIdx.x < 2048) {
        const int o = blockIdx.x;
        const float* row = w_out + (size_t)o * BDIM;
        for (int i = t; i < BDIM / 4; i += 256)
            ((float4*)v)[i] = ((const float4*)row)[i];
        __syncthreads();
        for (int l = LOG_DIM - 1; l >= 0; --l) {
            #pragma unroll
            for (int pp = 0; pp < 4; ++pp) {
                int p = t + pp * 256;
                int j = p >> l;
                int s = p & ((1 << l) - 1);
                int i0 = (j << (l + 1)) | s;
                int i1 = i0 + (1 << l);
                float a = a_pad[l * (BDIM / 2) + j];
                float b = b_pad[l * (BDIM / 2) + j];
                float x0 = v[i0], x1 = v[i1];
                v[i0] = a * x0 - b * x1;
                v[i1] = b * x0 + a * x1;
            }
            __syncthreads();
        }
        union { bf16 h[8]; int4 vv; } u;
        #pragma unroll
        for (int j = 0; j < 8; ++j) u.h[j] = __float2bfloat16(v[t * 8 + j]);
        *(int4*)(woutb + (size_t)o * BDIM + t * 8) = u.vv;
    } else if (blockIdx.x < 6144) {
        const int b = blockIdx.x - 2048;
        const int bx = b & 63, by = b >> 6;
        const int tx = t & 31, ty = t >> 5;
        #pragma unroll
        for (int r = ty; r < 32; r += 8)
            tile[r][tx] = w_in[(size_t)(by * 32 + r) * NFEAT + bx * 32 + tx];
        __syncthreads();
        #pragma unroll
        for (int r = ty; r < 32; r += 8)
            wint[(size_t)(bx * 32 + r) * NFEAT + by * 32 + tx] = __float2bfloat16(tile[tx][r]);
    } else {
        cvt_chunk(x, x_bf, 768 + (blockIdx.x - 6144), t);
    }
}

// ---------------------------------------------------------------------------
// prep2: splitk M-GEMM [0,1024) || x cvt chunks [1024,1792)
// ---------------------------------------------------------------------------
__global__ __launch_bounds__(256, 2) void prep2(const bf16* __restrict__ Aw,
                                                const bf16* __restrict__ Btw,
                                                bf16* __restrict__ Cpart,
                                                const float* __restrict__ x,
                                                bf16* __restrict__ x_bf) {
    __shared__ bf16 sA[128 * 32];
    __shared__ bf16 sB[128 * 32];
    const int tid = threadIdx.x;

    if (blockIdx.x >= 1024) {
        cvt_chunk(x, x_bf, blockIdx.x - 1024, tid);
        return;
    }

    constexpr int BK = 32, LDA = 2048, KLEN = 512, NN = 2048;
    const int sk = blockIdx.x;
    const int bx = sk & 15, by = (sk >> 4) & 15, kz = sk >> 8;
    const bf16* A = Aw + kz * KLEN;
    const bf16* Bt = Btw + kz * KLEN;
    bf16* C = Cpart + (size_t)kz * NN * NN;

    const int wave = tid >> 6, lane = tid & 63;
    const int wr = wave >> 1, wc = wave & 1;
    const int mBase = by * 128, nBase = bx * 128;

    const int r0 = tid >> 2, c0 = tid & 3;
    const int r1 = (256 + tid) >> 2;

    const bf16* gA0 = A + (size_t)(mBase + r0) * LDA + c0 * 8;
    const bf16* gA1 = A + (size_t)(mBase + r1) * LDA + c0 * 8;
    const bf16* gB0 = Bt + (size_t)(nBase + r0) * LDA + c0 * 8;
    const bf16* gB1 = Bt + (size_t)(nBase + r1) * LDA + c0 * 8;

    char* lA0 = (char*)sA + (wave * 64) * 16;
    char* lA1 = (char*)sA + (256 + wave * 64) * 16;
    char* lB0 = (char*)sB + (wave * 64) * 16;
    char* lB1 = (char*)sB + (256 + wave * 64) * 16;

    f32x4 acc[4][4];
    #pragma unroll
    for (int i = 0; i < 4; ++i)
        #pragma unroll
        for (int j = 0; j < 4; ++j) acc[i][j] = (f32x4){0.f, 0.f, 0.f, 0.f};

    const int aRow = wr * 64 + (lane & 15);
    const int bRow = wc * 64 + (lane & 15);
    const int kOff = (lane >> 4) * 8;

    for (int k0 = 0; k0 < KLEN; k0 += BK) {
        LOAD_LDS16(gA0, lA0);
        LOAD_LDS16(gA1, lA1);
        LOAD_LDS16(gB0, lB0);
        LOAD_LDS16(gB1, lB1);
        gA0 += BK; gA1 += BK; gB0 += BK; gB1 += BK;
        __syncthreads();
        bf16x8 af[4], bfr[4];
        #pragma unroll
        for (int mf = 0; mf < 4; ++mf)
            af[mf] = *reinterpret_cast<const bf16x8*>(&sA[(aRow + mf * 16) * BK + kOff]);
        #pragma unroll
        for (int nf = 0; nf < 4; ++nf)
            bfr[nf] = *reinterpret_cast<const bf16x8*>(&sB[(bRow + nf * 16) * BK + kOff]);
        #pragma unroll
        for (int mf = 0; mf < 4; ++mf)
            #pragma unroll
            for (int nf = 0; nf < 4; ++nf)
                acc[mf][nf] = __builtin_amdgcn_mfma_f32_16x16x32_bf16(
                    af[mf], bfr[nf], acc[mf][nf], 0, 0, 0);
        __syncthreads();
    }

    const int cRow0 = mBase + wr * 64 + (lane >> 4) * 4;
    const int cCol0 = nBase + wc * 64 + (lane & 15);
    #pragma unroll
    for (int mf = 0; mf < 4; ++mf)
        #pragma unroll
        for (int nf = 0; nf < 4; ++nf)
            #pragma unroll
            for (int r = 0; r < 4; ++r)
                C[(size_t)(cRow0 + mf * 16 + r) * NN + cCol0 + nf * 16] =
                    __float2bfloat16(acc[mf][nf][r]);
}

// ---------------------------------------------------------------------------
// add four bf16 partials -> bf16
// ---------------------------------------------------------------------------
__global__ __launch_bounds__(256) void addcvt4(const bf16* __restrict__ p,
                                               bf16* __restrict__ out) {
    size_t i = ((size_t)blockIdx.x * 256 + threadIdx.x) * 8;
    constexpr size_t STRIDE = (size_t)2048 * 2048;
    float s[8];
    #pragma unroll
    for (int j = 0; j < 8; ++j) s[j] = 0.f;
    #pragma unroll
    for (int z = 0; z < 4; ++z) {
        union { bf16 h[8]; int4 v; } a;
        a.v = *(const int4*)(p + z * STRIDE + i);
        #pragma unroll
        for (int j = 0; j < 8; ++j) s[j] += __bfloat162float(a.h[j]);
    }
    union { bf16 h[8]; int4 v; } o;
    #pragma unroll
    for (int j = 0; j < 8; ++j) o.h[j] = __float2bfloat16(s[j]);
    *(int4*)(out + i) = o.v;
}

// ---------------------------------------------------------------------------
// Main GEMM (8-phase schedule, mfma_32x32x16, FIXED swizzle r6->r7):
//   Conflict mechanism found r6: LDS pairs lane l with l+32; with slot =
//   ks*2+hi those lanes differ only in slot bit0 -> granule sets collide
//   2-way.  New involution: logical chunk s stored at phys slot swap(s)^sx
//   (swap = exchange slot bits 0<->1, self-inverse; sx = (row>>1)&3).
//   Read slot for (ks,hi) = (hi*2+ks)^sx -> l/l+32 granules differ by 2,
//   8-lane groups still cover all granules: conflict-free under BOTH
//   grouping models.  Stage source chunk = row*4 + swap((tid&3)^sx_row),
//   LDS dest stays linear (rule #21).
//   C/D layout (m74/m101): col=lane&31, row=(reg&3)+8*(reg>>2)+4*(lane>>5).
// ---------------------------------------------------------------------------
#define GK 2048
#define LDS_SLOT 65536
#define LDS_BOFF 32768
#define LDS_KH 16384

__global__ __launch_bounds__(512, 2) void gemm256(const bf16* __restrict__ A,
                                                  const bf16* __restrict__ Bt,
                                                  const float* __restrict__ bias,
                                                  float* __restrict__ C) {
    __shared__ __align__(16) char lds[131072];

    const int tid = threadIdx.x;
    const int wave = tid >> 6, lane = tid & 63;
    const int l31 = lane & 31, hi = lane >> 5;
    const int wm = wave >> 2, wn = wave & 3;

    // T1: bijective XCD swizzle (512 wgs, 512%8==0)
    const int bid = blockIdx.x;
    const int swz = (bid & 7) * 64 + (bid >> 3);
    const int bm = swz >> 3, bn = swz & 7;
    const int mBase = bm * 256, nBase = bn * 256;

    // stage source (pre-swizzled, swap-extended involution):
    //   src chunk = (tid & ~3) | swap((tid&3) ^ ((tid>>3)&3))
    const int px = (tid & 3) ^ ((tid >> 3) & 3);
    const int skc = ((px << 1) | (px >> 1)) & 3;       // swap(px)
    const int srow = tid >> 2;
    const bf16* gA = A + (size_t)(mBase + srow) * GK + skc * 8;
    const bf16* gB = Bt + (size_t)(nBase + srow) * GK + skc * 8;
    const int stgBase = wave * 1024;

    // read offsets: phys slot for (ks,hi) = (hi*2+ks) ^ sx, sx=(l31>>1)&3
    const int sx = (l31 >> 1) & 3;
    const int sl0 = (((hi << 1) | 0) ^ sx) << 4;       // ks=0
    const int sl1 = (((hi << 1) | 1) ^ sx) << 4;       // ks=1
    const int rowA = (wm * 128 + l31) * 64;
    const int rowB = LDS_BOFF + (wn * 64 + l31) * 64;

    f32x16 acc[4][2];
    #pragma unroll
    for (int i = 0; i < 4; ++i)
        #pragma unroll
        for (int j = 0; j < 2; ++j)
            #pragma unroll
            for (int r = 0; r < 16; ++r) acc[i][j][r] = 0.f;

    bf16x8 Aa[4], Ab[4], Ba[4], Bb[4];   // [mb*2+ks] / [nb*2+ks]

#define STG(GSRC, LDSC, KT, KH) do {                                        \
    const bf16* _g = (GSRC) + (KT) * 64 + (KH) * 32;                        \
    LOAD_LDS16(_g, lds + (LDSC) + stgBase);                                 \
    LOAD_LDS16(_g + (size_t)128 * GK, lds + (LDSC) + stgBase + 8192);       \
} while (0)

#define READP(AN, BN, SLOT, KH, MH, DOB) do {                               \
    const int _rb = (SLOT) * LDS_SLOT + (KH) * LDS_KH;                      \
    _Pragma("unroll")                                                       \
    for (int _mb = 0; _mb < 2; ++_mb) {                                     \
        AN[_mb * 2 + 0] = *(const bf16x8*)(lds + _rb + rowA + ((MH) * 2 + _mb) * 2048 + sl0); \
        AN[_mb * 2 + 1] = *(const bf16x8*)(lds + _rb + rowA + ((MH) * 2 + _mb) * 2048 + sl1); \
    }                                                                       \
    if (DOB) {                                                              \
        _Pragma("unroll")                                                   \
        for (int _nb = 0; _nb < 2; ++_nb) {                                 \
            BN[_nb * 2 + 0] = *(const bf16x8*)(lds + _rb + rowB + _nb * 2048 + sl0); \
            BN[_nb * 2 + 1] = *(const bf16x8*)(lds + _rb + rowB + _nb * 2048 + sl1); \
        }                                                                   \
    }                                                                       \
} while (0)

    // prologue: slot0 complete (tile 0), then 3 regions of slot1 (tile 1)
    STG(gA, 0 * LDS_SLOT + 0, 0, 0);
    STG(gB, 0 * LDS_SLOT + LDS_BOFF + 0, 0, 0);
    STG(gA, 0 * LDS_SLOT + LDS_KH, 0, 1);
    STG(gB, 0 * LDS_SLOT + LDS_BOFF + LDS_KH, 0, 1);
    STG(gA, 1 * LDS_SLOT + 0, 1, 0);
    STG(gB, 1 * LDS_SLOT + LDS_BOFF + 0, 1, 0);
    STG(gB, 1 * LDS_SLOT + LDS_BOFF + LDS_KH, 1, 1);
    asm volatile("s_waitcnt vmcnt(6)");   // slot0's 8 loads landed
    __builtin_amdgcn_s_barrier();
    READP(Aa, Ba, 0, 0, 0, 1);            // regs for phase 0

    // PH: compute (MH) from CURA/CURB; prefetch (RS,RKH,RMH) into NXTA/NXTB;
    //     stage one freed region; vmcnt(6) only at p3/p7 (before barrier#1).
#define PH(CURA, CURB, NXTA, NXTB, MH, RS, RKH, RMH, RDOB, SGSRC, SLDS, SKT, SKH, DOVM) do { \
    STG(SGSRC, SLDS, SKT, SKH);                                             \
    if (DOVM) asm volatile("s_waitcnt vmcnt(6)");                           \
    __builtin_amdgcn_s_barrier();                                           \
    READP(NXTA, NXTB, RS, RKH, RMH, RDOB);                                  \
    __builtin_amdgcn_s_setprio(1);                                          \
    _Pragma("unroll")                                                       \
    for (int _ks = 0; _ks < 2; ++_ks)                                       \
        _Pragma("unroll")                                                   \
        for (int _mb = 0; _mb < 2; ++_mb)                                   \
            _Pragma("unroll")                                               \
            for (int _nb = 0; _nb < 2; ++_nb)                               \
                acc[(MH) * 2 + _mb][_nb] = __builtin_amdgcn_mfma_f32_32x32x16_bf16( \
                    CURA[_mb * 2 + _ks], CURB[_nb * 2 + _ks],               \
                    acc[(MH) * 2 + _mb][_nb], 0, 0, 0);                     \
    __builtin_amdgcn_s_setprio(0);                                          \
    __builtin_amdgcn_s_barrier();                                           \
} while (0)

    // 32 K-tiles, 2 per iteration; ledger identical to r3/r4 (HW-verified);
    // prefetch = next phase's compute coords.
    for (int it = 0; it < 16; ++it) {
        const int t0 = 2 * it;
        const int t1 = (t0 + 1) & 31, t2 = (t0 + 2) & 31, t3 = (t0 + 3) & 31;
        PH(Aa, Ba, Ab, Bb, 0, 0, 0, 1, 0, gA, 1 * LDS_SLOT + LDS_KH,            t1, 1, 0);
        PH(Ab, Ba, Aa, Bb, 1, 0, 1, 0, 1, gB, 0 * LDS_SLOT + LDS_BOFF,          t2, 0, 0);
        PH(Aa, Bb, Ab, Ba, 0, 0, 1, 1, 0, gA, 0 * LDS_SLOT + 0,                 t2, 0, 0);
        PH(Ab, Bb, Aa, Ba, 1, 1, 0, 0, 1, gB, 0 * LDS_SLOT + LDS_BOFF + LDS_KH, t2, 1, 1);
        PH(Aa, Ba, Ab, Bb, 0, 1, 0, 1, 0, gA, 0 * LDS_SLOT + LDS_KH,            t2, 1, 0);
        PH(Ab, Ba, Aa, Bb, 1, 1, 1, 0, 1, gB, 1 * LDS_SLOT + LDS_BOFF,          t3, 0, 0);
        PH(Aa, Bb, Ab, Ba, 0, 1, 1, 1, 0, gA, 1 * LDS_SLOT + 0,                 t3, 0, 0);
        PH(Ab, Bb, Aa, Ba, 1, 0, 0, 0, 1, gB, 1 * LDS_SLOT + LDS_BOFF + LDS_KH, t3, 1, 1);
    }

    // epilogue: 32x32 C/D layout col=lane&31, row=(reg&3)+8*(reg>>2)+4*hi
    #pragma unroll
    for (int mb = 0; mb < 4; ++mb) {
        #pragma unroll
        for (int nb = 0; nb < 2; ++nb) {
            const int col = nBase + wn * 64 + nb * 32 + l31;
            const float bv = bias[col];
            const int rbase = mBase + wm * 128 + mb * 32 + 4 * hi;
            #pragma unroll
            for (int r = 0; r < 16; ++r) {
                const int row = rbase + (r & 3) + 8 * (r >> 2);
                C[(size_t)row * GK + col] = acc[mb][nb][r] + bv;
            }
        }
    }
#undef PH
#undef READP
#undef STG
}

// ---------------------------------------------------------------------------
// launch
// ---------------------------------------------------------------------------
extern "C" void kernel_launch(void* const* d_in, const int* in_sizes, int n_in,
                              void* d_out, int out_size, void* d_ws, size_t ws_size,
                              hipStream_t stream) {
    const float* x     = (const float*)d_in[0];
    const float* w_in  = (const float*)d_in[1];
    const float* w_out = (const float*)d_in[2];
    const float* b_out = (const float*)d_in[3];
    const float* a_pad = (const float*)d_in[4];
    const float* b_pad = (const float*)d_in[5];
    float* out = (float*)d_out;

    char* ws = (char*)d_ws;
    bf16* x_bf  = (bf16*)ws;                        // 67,108,864 B
    bf16* woutb = (bf16*)(ws + (size_t)67108864);   //  8,388,608 B
    bf16* wint  = (bf16*)(ws + (size_t)75497472);   //  8,388,608 B
    bf16* mcomb = (bf16*)(ws + (size_t)83886080);   //  8,388,608 B  (ws total 92 MB)

    // split-K partials live in d_out (134 MB, fully overwritten by gemm256)
    bf16* part = (bf16*)d_out;                      // 4 x 8 MB

    prep1<<<dim3(6400), dim3(256), 0, stream>>>(w_out, a_pad, b_pad, w_in,
                                                woutb, wint, x, x_bf);
    prep2<<<dim3(1792), dim3(256), 0, stream>>>(woutb, wint, part, x, x_bf);
    addcvt4<<<dim3(NFEAT * BDIM / (256 * 8)), dim3(256), 0, stream>>>(part, mcomb);
    gemm256<<<dim3((BATCH / 256) * (NFEAT / 256)), dim3(512), 0, stream>>>(
        x_bf, mcomb, b_out, out);
}

// Round 8
// 237.963 us; speedup vs baseline: 1.0011x; 1.0011x over previous
//
#include <hip/hip_runtime.h>
#include <hip/hip_bf16.h>

using bf16 = __hip_bfloat16;
using bf16x8 = __attribute__((ext_vector_type(8))) __bf16;
using f32x4 = __attribute__((ext_vector_type(4))) float;
using f32x16 = __attribute__((ext_vector_type(16))) float;

typedef const __attribute__((address_space(1))) void* gas_ptr;
typedef __attribute__((address_space(3))) void* las_ptr;
#define LOAD_LDS16(g, l) \
    __builtin_amdgcn_global_load_lds((gas_ptr)(const void*)(g), (las_ptr)(void*)(l), 16, 0, 0)

#define LOG_DIM 11
#define BDIM 2048
#define NFEAT 2048
#define BATCH 16384

__device__ __forceinline__ void cvt_chunk(const float* __restrict__ x,
                                          bf16* __restrict__ x_bf, int chunk, int tid) {
    #pragma unroll
    for (int it = 0; it < 16; ++it) {
        size_t i = ((size_t)chunk * 16 + it) * 2048 + tid * 8;
        float4 v0 = *(const float4*)(x + i);
        float4 v1 = *(const float4*)(x + i + 4);
        union { bf16 h[8]; int4 v; } u;
        u.h[0] = __float2bfloat16(v0.x); u.h[1] = __float2bfloat16(v0.y);
        u.h[2] = __float2bfloat16(v0.z); u.h[3] = __float2bfloat16(v0.w);
        u.h[4] = __float2bfloat16(v1.x); u.h[5] = __float2bfloat16(v1.y);
        u.h[6] = __float2bfloat16(v1.z); u.h[7] = __float2bfloat16(v1.w);
        *(int4*)(x_bf + i) = u.v;
    }
}

// ---------------------------------------------------------------------------
// prep1: butterfly_wout [0,2048) || transpose_cvt [2048,6144) || cvt [6144,6400)
// ---------------------------------------------------------------------------
__global__ __launch_bounds__(256) void prep1(const float* __restrict__ w_out,
                                             const float* __restrict__ a_pad,
                                             const float* __restrict__ b_pad,
                                             const float* __restrict__ w_in,
                                             bf16* __restrict__ woutb,
                                             bf16* __restrict__ wint,
                                             const float* __restrict__ x,
                                             bf16* __restrict__ x_bf) {
    __shared__ float v[BDIM];
    __shared__ float tile[32][33];
    const int t = threadIdx.x;
    if (blockIdx.x < 2048) {
        const int o = blockIdx.x;
        const float* row = w_out + (size_t)o * BDIM;
        for (int i = t; i < BDIM / 4; i += 256)
            ((float4*)v)[i] = ((const float4*)row)[i];
        __syncthreads();
        for (int l = LOG_DIM - 1; l >= 0; --l) {
            #pragma unroll
            for (int pp = 0; pp < 4; ++pp) {
                int p = t + pp * 256;
                int j = p >> l;
                int s = p & ((1 << l) - 1);
                int i0 = (j << (l + 1)) | s;
                int i1 = i0 + (1 << l);
                float a = a_pad[l * (BDIM / 2) + j];
                float b = b_pad[l * (BDIM / 2) + j];
                float x0 = v[i0], x1 = v[i1];
                v[i0] = a * x0 - b * x1;
                v[i1] = b * x0 + a * x1;
            }
            __syncthreads();
        }
        union { bf16 h[8]; int4 vv; } u;
        #pragma unroll
        for (int j = 0; j < 8; ++j) u.h[j] = __float2bfloat16(v[t * 8 + j]);
        *(int4*)(woutb + (size_t)o * BDIM + t * 8) = u.vv;
    } else if (blockIdx.x < 6144) {
        const int b = blockIdx.x - 2048;
        const int bx = b & 63, by = b >> 6;
        const int tx = t & 31, ty = t >> 5;
        #pragma unroll
        for (int r = ty; r < 32; r += 8)
            tile[r][tx] = w_in[(size_t)(by * 32 + r) * NFEAT + bx * 32 + tx];
        __syncthreads();
        #pragma unroll
        for (int r = ty; r < 32; r += 8)
            wint[(size_t)(bx * 32 + r) * NFEAT + by * 32 + tx] = __float2bfloat16(tile[tx][r]);
    } else {
        cvt_chunk(x, x_bf, 768 + (blockIdx.x - 6144), t);
    }
}

// ---------------------------------------------------------------------------
// prep2: splitk M-GEMM [0,1024) || x cvt chunks [1024,1792)
// ---------------------------------------------------------------------------
__global__ __launch_bounds__(256, 2) void prep2(const bf16* __restrict__ Aw,
                                                const bf16* __restrict__ Btw,
                                                bf16* __restrict__ Cpart,
                                                const float* __restrict__ x,
                                                bf16* __restrict__ x_bf) {
    __shared__ bf16 sA[128 * 32];
    __shared__ bf16 sB[128 * 32];
    const int tid = threadIdx.x;

    if (blockIdx.x >= 1024) {
        cvt_chunk(x, x_bf, blockIdx.x - 1024, tid);
        return;
    }

    constexpr int BK = 32, LDA = 2048, KLEN = 512, NN = 2048;
    const int sk = blockIdx.x;
    const int bx = sk & 15, by = (sk >> 4) & 15, kz = sk >> 8;
    const bf16* A = Aw + kz * KLEN;
    const bf16* Bt = Btw + kz * KLEN;
    bf16* C = Cpart + (size_t)kz * NN * NN;

    const int wave = tid >> 6, lane = tid & 63;
    const int wr = wave >> 1, wc = wave & 1;
    const int mBase = by * 128, nBase = bx * 128;

    const int r0 = tid >> 2, c0 = tid & 3;
    const int r1 = (256 + tid) >> 2;

    const bf16* gA0 = A + (size_t)(mBase + r0) * LDA + c0 * 8;
    const bf16* gA1 = A + (size_t)(mBase + r1) * LDA + c0 * 8;
    const bf16* gB0 = Bt + (size_t)(nBase + r0) * LDA + c0 * 8;
    const bf16* gB1 = Bt + (size_t)(nBase + r1) * LDA + c0 * 8;

    char* lA0 = (char*)sA + (wave * 64) * 16;
    char* lA1 = (char*)sA + (256 + wave * 64) * 16;
    char* lB0 = (char*)sB + (wave * 64) * 16;
    char* lB1 = (char*)sB + (256 + wave * 64) * 16;

    f32x4 acc[4][4];
    #pragma unroll
    for (int i = 0; i < 4; ++i)
        #pragma unroll
        for (int j = 0; j < 4; ++j) acc[i][j] = (f32x4){0.f, 0.f, 0.f, 0.f};

    const int aRow = wr * 64 + (lane & 15);
    const int bRow = wc * 64 + (lane & 15);
    const int kOff = (lane >> 4) * 8;

    for (int k0 = 0; k0 < KLEN; k0 += BK) {
        LOAD_LDS16(gA0, lA0);
        LOAD_LDS16(gA1, lA1);
        LOAD_LDS16(gB0, lB0);
        LOAD_LDS16(gB1, lB1);
        gA0 += BK; gA1 += BK; gB0 += BK; gB1 += BK;
        __syncthreads();
        bf16x8 af[4], bfr[4];
        #pragma unroll
        for (int mf = 0; mf < 4; ++mf)
            af[mf] = *reinterpret_cast<const bf16x8*>(&sA[(aRow + mf * 16) * BK + kOff]);
        #pragma unroll
        for (int nf = 0; nf < 4; ++nf)
            bfr[nf] = *reinterpret_cast<const bf16x8*>(&sB[(bRow + nf * 16) * BK + kOff]);
        #pragma unroll
        for (int mf = 0; mf < 4; ++mf)
            #pragma unroll
            for (int nf = 0; nf < 4; ++nf)
                acc[mf][nf] = __builtin_amdgcn_mfma_f32_16x16x32_bf16(
                    af[mf], bfr[nf], acc[mf][nf], 0, 0, 0);
        __syncthreads();
    }

    const int cRow0 = mBase + wr * 64 + (lane >> 4) * 4;
    const int cCol0 = nBase + wc * 64 + (lane & 15);
    #pragma unroll
    for (int mf = 0; mf < 4; ++mf)
        #pragma unroll
        for (int nf = 0; nf < 4; ++nf)
            #pragma unroll
            for (int r = 0; r < 4; ++r)
                C[(size_t)(cRow0 + mf * 16 + r) * NN + cCol0 + nf * 16] =
                    __float2bfloat16(acc[mf][nf][r]);
}

// ---------------------------------------------------------------------------
// add four bf16 partials -> bf16
// ---------------------------------------------------------------------------
__global__ __launch_bounds__(256) void addcvt4(const bf16* __restrict__ p,
                                               bf16* __restrict__ out) {
    size_t i = ((size_t)blockIdx.x * 256 + threadIdx.x) * 8;
    constexpr size_t STRIDE = (size_t)2048 * 2048;
    float s[8];
    #pragma unroll
    for (int j = 0; j < 8; ++j) s[j] = 0.f;
    #pragma unroll
    for (int z = 0; z < 4; ++z) {
        union { bf16 h[8]; int4 v; } a;
        a.v = *(const int4*)(p + z * STRIDE + i);
        #pragma unroll
        for (int j = 0; j < 8; ++j) s[j] += __bfloat162float(a.h[j]);
    }
    union { bf16 h[8]; int4 v; } o;
    #pragma unroll
    for (int j = 0; j < 8; ++j) o.h[j] = __float2bfloat16(s[j]);
    *(int4*)(out + i) = o.v;
}

// ---------------------------------------------------------------------------
// Main GEMM (8-phase schedule, mfma_32x32x16, swizzle FIX v3 r7->r8):
//   Conflict model (fits r4=0, r6=r7=1.271e7 exactly): LDS services quads
//   {l, l+16, l+32, l+48} concurrently.  Quad rows = {r, r+16, r, r+16};
//   rows 16 apart share bank phase ((row*16)%32 equal), so their slots must
//   differ.  r6/r7's sx=((l31>>1)&3) is invariant under l31+=16 -> same
//   slot -> 2-way conflict every read.  FIX: sx = ((l31>>1)&3) ^
//   ((l31>>4)<<1), slot = (ks*2 + hi) ^ sx.  Quad slots = {s, s^1 (hi),
//   s^2 (rowbit4), s^3} all distinct; consecutive-8 groups still cover all
//   8 granules (slot cycles via (l>>1)&3, parity splits x4).  Stage source
//   gains the matching ((tid>>6)&1)<<1 term (srow=tid>>2, sx(srow) bit1 =
//   srow bit4 = tid bit6); +512 issue (row+128) leaves sx unchanged.
//   XOR involution applied on BOTH sides (rule #21); LDS dest stays linear.
//   C/D layout (m74/m101): col=lane&31, row=(reg&3)+8*(reg>>2)+4*(lane>>5).
// ---------------------------------------------------------------------------
#define GK 2048
#define LDS_SLOT 65536
#define LDS_BOFF 32768
#define LDS_KH 16384

__global__ __launch_bounds__(512, 2) void gemm256(const bf16* __restrict__ A,
                                                  const bf16* __restrict__ Bt,
                                                  const float* __restrict__ bias,
                                                  float* __restrict__ C) {
    __shared__ __align__(16) char lds[131072];

    const int tid = threadIdx.x;
    const int wave = tid >> 6, lane = tid & 63;
    const int l31 = lane & 31, hi = lane >> 5;
    const int wm = wave >> 2, wn = wave & 3;

    // T1: bijective XCD swizzle (512 wgs, 512%8==0)
    const int bid = blockIdx.x;
    const int swz = (bid & 7) * 64 + (bid >> 3);
    const int bm = swz >> 3, bn = swz & 7;
    const int mBase = bm * 256, nBase = bn * 256;

    // stage source (pre-swizzled): phys slot tid&3 holds logical slot
    //   (tid&3) ^ sx(srow), sx(srow) = ((tid>>3)&3) ^ (((tid>>6)&1)<<1)
    const int sxr = ((tid >> 3) & 3) ^ (((tid >> 6) & 1) << 1);
    const int skc = (tid & 3) ^ sxr;
    const int srow = tid >> 2;
    const bf16* gA = A + (size_t)(mBase + srow) * GK + skc * 8;
    const bf16* gB = Bt + (size_t)(nBase + srow) * GK + skc * 8;
    const int stgBase = wave * 1024;

    // read offsets: phys slot for (ks,hi) = (ks*2 + hi) ^ sx,
    //   sx = ((l31>>1)&3) ^ ((l31>>4)<<1)
    const int sx = ((l31 >> 1) & 3) ^ (((l31 >> 4) & 1) << 1);
    const int sl0 = ((0 + hi) ^ sx) << 4;       // ks=0
    const int sl1 = ((2 + hi) ^ sx) << 4;       // ks=1
    const int rowA = (wm * 128 + l31) * 64;
    const int rowB = LDS_BOFF + (wn * 64 + l31) * 64;

    f32x16 acc[4][2];
    #pragma unroll
    for (int i = 0; i < 4; ++i)
        #pragma unroll
        for (int j = 0; j < 2; ++j)
            #pragma unroll
            for (int r = 0; r < 16; ++r) acc[i][j][r] = 0.f;

    bf16x8 Aa[4], Ab[4], Ba[4], Bb[4];   // [mb*2+ks] / [nb*2+ks]

#define STG(GSRC, LDSC, KT, KH) do {                                        \
    const bf16* _g = (GSRC) + (KT) * 64 + (KH) * 32;                        \
    LOAD_LDS16(_g, lds + (LDSC) + stgBase);                                 \
    LOAD_LDS16(_g + (size_t)128 * GK, lds + (LDSC) + stgBase + 8192);       \
} while (0)

#define READP(AN, BN, SLOT, KH, MH, DOB) do {                               \
    const int _rb = (SLOT) * LDS_SLOT + (KH) * LDS_KH;                      \
    _Pragma("unroll")                                                       \
    for (int _mb = 0; _mb < 2; ++_mb) {                                     \
        AN[_mb * 2 + 0] = *(const bf16x8*)(lds + _rb + rowA + ((MH) * 2 + _mb) * 2048 + sl0); \
        AN[_mb * 2 + 1] = *(const bf16x8*)(lds + _rb + rowA + ((MH) * 2 + _mb) * 2048 + sl1); \
    }                                                                       \
    if (DOB) {                                                              \
        _Pragma("unroll")                                                   \
        for (int _nb = 0; _nb < 2; ++_nb) {                                 \
            BN[_nb * 2 + 0] = *(const bf16x8*)(lds + _rb + rowB + _nb * 2048 + sl0); \
            BN[_nb * 2 + 1] = *(const bf16x8*)(lds + _rb + rowB + _nb * 2048 + sl1); \
        }                                                                   \
    }                                                                       \
} while (0)

    // prologue: slot0 complete (tile 0), then 3 regions of slot1 (tile 1)
    STG(gA, 0 * LDS_SLOT + 0, 0, 0);
    STG(gB, 0 * LDS_SLOT + LDS_BOFF + 0, 0, 0);
    STG(gA, 0 * LDS_SLOT + LDS_KH, 0, 1);
    STG(gB, 0 * LDS_SLOT + LDS_BOFF + LDS_KH, 0, 1);
    STG(gA, 1 * LDS_SLOT + 0, 1, 0);
    STG(gB, 1 * LDS_SLOT + LDS_BOFF + 0, 1, 0);
    STG(gB, 1 * LDS_SLOT + LDS_BOFF + LDS_KH, 1, 1);
    asm volatile("s_waitcnt vmcnt(6)");   // slot0's 8 loads landed
    __builtin_amdgcn_s_barrier();
    READP(Aa, Ba, 0, 0, 0, 1);            // regs for phase 0

    // PH: compute (MH) from CURA/CURB; prefetch (RS,RKH,RMH) into NXTA/NXTB;
    //     stage one freed region; vmcnt(6) only at p3/p7 (before barrier#1).
#define PH(CURA, CURB, NXTA, NXTB, MH, RS, RKH, RMH, RDOB, SGSRC, SLDS, SKT, SKH, DOVM) do { \
    STG(SGSRC, SLDS, SKT, SKH);                                             \
    if (DOVM) asm volatile("s_waitcnt vmcnt(6)");                           \
    __builtin_amdgcn_s_barrier();                                           \
    READP(NXTA, NXTB, RS, RKH, RMH, RDOB);                                  \
    __builtin_amdgcn_s_setprio(1);                                          \
    _Pragma("unroll")                                                       \
    for (int _ks = 0; _ks < 2; ++_ks)                                       \
        _Pragma("unroll")                                                   \
        for (int _mb = 0; _mb < 2; ++_mb)                                   \
            _Pragma("unroll")                                               \
            for (int _nb = 0; _nb < 2; ++_nb)                               \
                acc[(MH) * 2 + _mb][_nb] = __builtin_amdgcn_mfma_f32_32x32x16_bf16( \
                    CURA[_mb * 2 + _ks], CURB[_nb * 2 + _ks],               \
                    acc[(MH) * 2 + _mb][_nb], 0, 0, 0);                     \
    __builtin_amdgcn_s_setprio(0);                                          \
    __builtin_amdgcn_s_barrier();                                           \
} while (0)

    // 32 K-tiles, 2 per iteration; ledger identical to r3/r4 (HW-verified);
    // prefetch = next phase's compute coords.
    for (int it = 0; it < 16; ++it) {
        const int t0 = 2 * it;
        const int t1 = (t0 + 1) & 31, t2 = (t0 + 2) & 31, t3 = (t0 + 3) & 31;
        PH(Aa, Ba, Ab, Bb, 0, 0, 0, 1, 0, gA, 1 * LDS_SLOT + LDS_KH,            t1, 1, 0);
        PH(Ab, Ba, Aa, Bb, 1, 0, 1, 0, 1, gB, 0 * LDS_SLOT + LDS_BOFF,          t2, 0, 0);
        PH(Aa, Bb, Ab, Ba, 0, 0, 1, 1, 0, gA, 0 * LDS_SLOT + 0,                 t2, 0, 0);
        PH(Ab, Bb, Aa, Ba, 1, 1, 0, 0, 1, gB, 0 * LDS_SLOT + LDS_BOFF + LDS_KH, t2, 1, 1);
        PH(Aa, Ba, Ab, Bb, 0, 1, 0, 1, 0, gA, 0 * LDS_SLOT + LDS_KH,            t2, 1, 0);
        PH(Ab, Ba, Aa, Bb, 1, 1, 1, 0, 1, gB, 1 * LDS_SLOT + LDS_BOFF,          t3, 0, 0);
        PH(Aa, Bb, Ab, Ba, 0, 1, 1, 1, 0, gA, 1 * LDS_SLOT + 0,                 t3, 0, 0);
        PH(Ab, Bb, Aa, Ba, 1, 0, 0, 0, 1, gB, 1 * LDS_SLOT + LDS_BOFF + LDS_KH, t3, 1, 1);
    }

    // epilogue: 32x32 C/D layout col=lane&31, row=(reg&3)+8*(reg>>2)+4*hi
    #pragma unroll
    for (int mb = 0; mb < 4; ++mb) {
        #pragma unroll
        for (int nb = 0; nb < 2; ++nb) {
            const int col = nBase + wn * 64 + nb * 32 + l31;
            const float bv = bias[col];
            const int rbase = mBase + wm * 128 + mb * 32 + 4 * hi;
            #pragma unroll
            for (int r = 0; r < 16; ++r) {
                const int row = rbase + (r & 3) + 8 * (r >> 2);
                C[(size_t)row * GK + col] = acc[mb][nb][r] + bv;
            }
        }
    }
#undef PH
#undef READP
#undef STG
}

// ---------------------------------------------------------------------------
// launch
// ---------------------------------------------------------------------------
extern "C" void kernel_launch(void* const* d_in, const int* in_sizes, int n_in,
                              void* d_out, int out_size, void* d_ws, size_t ws_size,
                              hipStream_t stream) {
    const float* x     = (const float*)d_in[0];
    const float* w_in  = (const float*)d_in[1];
    const float* w_out = (const float*)d_in[2];
    const float* b_out = (const float*)d_in[3];
    const float* a_pad = (const float*)d_in[4];
    const float* b_pad = (const float*)d_in[5];
    float* out = (float*)d_out;

    char* ws = (char*)d_ws;
    bf16* x_bf  = (bf16*)ws;                        // 67,108,864 B
    bf16* woutb = (bf16*)(ws + (size_t)67108864);   //  8,388,608 B
    bf16* wint  = (bf16*)(ws + (size_t)75497472);   //  8,388,608 B
    bf16* mcomb = (bf16*)(ws + (size_t)83886080);   //  8,388,608 B  (ws total 92 MB)

    // split-K partials live in d_out (134 MB, fully overwritten by gemm256)
    bf16* part = (bf16*)d_out;                      // 4 x 8 MB

    prep1<<<dim3(6400), dim3(256), 0, stream>>>(w_out, a_pad, b_pad, w_in,
                                                woutb, wint, x, x_bf);
    prep2<<<dim3(1792), dim3(256), 0, stream>>>(woutb, wint, part, x, x_bf);
    addcvt4<<<dim3(NFEAT * BDIM / (256 * 8)), dim3(256), 0, stream>>>(part, mcomb);
    gemm256<<<dim3((BATCH / 256) * (NFEAT / 256)), dim3(512), 0, stream>>>(
        x_bf, mcomb, b_out, out);
}

// Round 9
// 228.003 us; speedup vs baseline: 1.0448x; 1.0437x over previous
//
#include <hip/hip_runtime.h>
#include <hip/hip_bf16.h>

using bf16 = __hip_bfloat16;
using bf16x8 = __attribute__((ext_vector_type(8))) __bf16;
using f32x4 = __attribute__((ext_vector_type(4))) float;

typedef const __attribute__((address_space(1))) void* gas_ptr;
typedef __attribute__((address_space(3))) void* las_ptr;
#define LOAD_LDS16(g, l) \
    __builtin_amdgcn_global_load_lds((gas_ptr)(const void*)(g), (las_ptr)(void*)(l), 16, 0, 0)

#define LOG_DIM 11
#define BDIM 2048
#define NFEAT 2048
#define BATCH 16384

__device__ __forceinline__ void cvt_chunk(const float* __restrict__ x,
                                          bf16* __restrict__ x_bf, int chunk, int tid) {
    #pragma unroll
    for (int it = 0; it < 16; ++it) {
        size_t i = ((size_t)chunk * 16 + it) * 2048 + tid * 8;
        float4 v0 = *(const float4*)(x + i);
        float4 v1 = *(const float4*)(x + i + 4);
        union { bf16 h[8]; int4 v; } u;
        u.h[0] = __float2bfloat16(v0.x); u.h[1] = __float2bfloat16(v0.y);
        u.h[2] = __float2bfloat16(v0.z); u.h[3] = __float2bfloat16(v0.w);
        u.h[4] = __float2bfloat16(v1.x); u.h[5] = __float2bfloat16(v1.y);
        u.h[6] = __float2bfloat16(v1.z); u.h[7] = __float2bfloat16(v1.w);
        *(int4*)(x_bf + i) = u.v;
    }
}

// ---------------------------------------------------------------------------
// prep1: butterfly_wout [0,2048) || transpose_cvt [2048,6144) || cvt [6144,6400)
// ---------------------------------------------------------------------------
__global__ __launch_bounds__(256) void prep1(const float* __restrict__ w_out,
                                             const float* __restrict__ a_pad,
                                             const float* __restrict__ b_pad,
                                             const float* __restrict__ w_in,
                                             bf16* __restrict__ woutb,
                                             bf16* __restrict__ wint,
                                             const float* __restrict__ x,
                                             bf16* __restrict__ x_bf) {
    __shared__ float v[BDIM];
    __shared__ float tile[32][33];
    const int t = threadIdx.x;
    if (blockIdx.x < 2048) {
        const int o = blockIdx.x;
        const float* row = w_out + (size_t)o * BDIM;
        for (int i = t; i < BDIM / 4; i += 256)
            ((float4*)v)[i] = ((const float4*)row)[i];
        __syncthreads();
        for (int l = LOG_DIM - 1; l >= 0; --l) {
            #pragma unroll
            for (int pp = 0; pp < 4; ++pp) {
                int p = t + pp * 256;
                int j = p >> l;
                int s = p & ((1 << l) - 1);
                int i0 = (j << (l + 1)) | s;
                int i1 = i0 + (1 << l);
                float a = a_pad[l * (BDIM / 2) + j];
                float b = b_pad[l * (BDIM / 2) + j];
                float x0 = v[i0], x1 = v[i1];
                v[i0] = a * x0 - b * x1;
                v[i1] = b * x0 + a * x1;
            }
            __syncthreads();
        }
        union { bf16 h[8]; int4 vv; } u;
        #pragma unroll
        for (int j = 0; j < 8; ++j) u.h[j] = __float2bfloat16(v[t * 8 + j]);
        *(int4*)(woutb + (size_t)o * BDIM + t * 8) = u.vv;
    } else if (blockIdx.x < 6144) {
        const int b = blockIdx.x - 2048;
        const int bx = b & 63, by = b >> 6;
        const int tx = t & 31, ty = t >> 5;
        #pragma unroll
        for (int r = ty; r < 32; r += 8)
            tile[r][tx] = w_in[(size_t)(by * 32 + r) * NFEAT + bx * 32 + tx];
        __syncthreads();
        #pragma unroll
        for (int r = ty; r < 32; r += 8)
            wint[(size_t)(bx * 32 + r) * NFEAT + by * 32 + tx] = __float2bfloat16(tile[tx][r]);
    } else {
        cvt_chunk(x, x_bf, 768 + (blockIdx.x - 6144), t);
    }
}

// ---------------------------------------------------------------------------
// prep2: splitk M-GEMM [0,1024) || x cvt chunks [1024,1792)
// ---------------------------------------------------------------------------
__global__ __launch_bounds__(256, 2) void prep2(const bf16* __restrict__ Aw,
                                                const bf16* __restrict__ Btw,
                                                bf16* __restrict__ Cpart,
                                                const float* __restrict__ x,
                                                bf16* __restrict__ x_bf) {
    __shared__ bf16 sA[128 * 32];
    __shared__ bf16 sB[128 * 32];
    const int tid = threadIdx.x;

    if (blockIdx.x >= 1024) {
        cvt_chunk(x, x_bf, blockIdx.x - 1024, tid);
        return;
    }

    constexpr int BK = 32, LDA = 2048, KLEN = 512, NN = 2048;
    const int sk = blockIdx.x;
    const int bx = sk & 15, by = (sk >> 4) & 15, kz = sk >> 8;
    const bf16* A = Aw + kz * KLEN;
    const bf16* Bt = Btw + kz * KLEN;
    bf16* C = Cpart + (size_t)kz * NN * NN;

    const int wave = tid >> 6, lane = tid & 63;
    const int wr = wave >> 1, wc = wave & 1;
    const int mBase = by * 128, nBase = bx * 128;

    const int r0 = tid >> 2, c0 = tid & 3;
    const int r1 = (256 + tid) >> 2;

    const bf16* gA0 = A + (size_t)(mBase + r0) * LDA + c0 * 8;
    const bf16* gA1 = A + (size_t)(mBase + r1) * LDA + c0 * 8;
    const bf16* gB0 = Bt + (size_t)(nBase + r0) * LDA + c0 * 8;
    const bf16* gB1 = Bt + (size_t)(nBase + r1) * LDA + c0 * 8;

    char* lA0 = (char*)sA + (wave * 64) * 16;
    char* lA1 = (char*)sA + (256 + wave * 64) * 16;
    char* lB0 = (char*)sB + (wave * 64) * 16;
    char* lB1 = (char*)sB + (256 + wave * 64) * 16;

    f32x4 acc[4][4];
    #pragma unroll
    for (int i = 0; i < 4; ++i)
        #pragma unroll
        for (int j = 0; j < 4; ++j) acc[i][j] = (f32x4){0.f, 0.f, 0.f, 0.f};

    const int aRow = wr * 64 + (lane & 15);
    const int bRow = wc * 64 + (lane & 15);
    const int kOff = (lane >> 4) * 8;

    for (int k0 = 0; k0 < KLEN; k0 += BK) {
        LOAD_LDS16(gA0, lA0);
        LOAD_LDS16(gA1, lA1);
        LOAD_LDS16(gB0, lB0);
        LOAD_LDS16(gB1, lB1);
        gA0 += BK; gA1 += BK; gB0 += BK; gB1 += BK;
        __syncthreads();
        bf16x8 af[4], bfr[4];
        #pragma unroll
        for (int mf = 0; mf < 4; ++mf)
            af[mf] = *reinterpret_cast<const bf16x8*>(&sA[(aRow + mf * 16) * BK + kOff]);
        #pragma unroll
        for (int nf = 0; nf < 4; ++nf)
            bfr[nf] = *reinterpret_cast<const bf16x8*>(&sB[(bRow + nf * 16) * BK + kOff]);
        #pragma unroll
        for (int mf = 0; mf < 4; ++mf)
            #pragma unroll
            for (int nf = 0; nf < 4; ++nf)
                acc[mf][nf] = __builtin_amdgcn_mfma_f32_16x16x32_bf16(
                    af[mf], bfr[nf], acc[mf][nf], 0, 0, 0);
        __syncthreads();
    }

    const int cRow0 = mBase + wr * 64 + (lane >> 4) * 4;
    const int cCol0 = nBase + wc * 64 + (lane & 15);
    #pragma unroll
    for (int mf = 0; mf < 4; ++mf)
        #pragma unroll
        for (int nf = 0; nf < 4; ++nf)
            #pragma unroll
            for (int r = 0; r < 4; ++r)
                C[(size_t)(cRow0 + mf * 16 + r) * NN + cCol0 + nf * 16] =
                    __float2bfloat16(acc[mf][nf][r]);
}

// ---------------------------------------------------------------------------
// add four bf16 partials -> bf16
// ---------------------------------------------------------------------------
__global__ __launch_bounds__(256) void addcvt4(const bf16* __restrict__ p,
                                               bf16* __restrict__ out) {
    size_t i = ((size_t)blockIdx.x * 256 + threadIdx.x) * 8;
    constexpr size_t STRIDE = (size_t)2048 * 2048;
    float s[8];
    #pragma unroll
    for (int j = 0; j < 8; ++j) s[j] = 0.f;
    #pragma unroll
    for (int z = 0; z < 4; ++z) {
        union { bf16 h[8]; int4 v; } a;
        a.v = *(const int4*)(p + z * STRIDE + i);
        #pragma unroll
        for (int j = 0; j < 8; ++j) s[j] += __bfloat162float(a.h[j]);
    }
    union { bf16 h[8]; int4 v; } o;
    #pragma unroll
    for (int j = 0; j < 8; ++j) o.h[j] = __float2bfloat16(s[j]);
    *(int4*)(out + i) = o.v;
}

// ---------------------------------------------------------------------------
// Main GEMM (16x16 MFMA, r3-verified swizzle, JIT-read m201 phase order):
//   Phase p computes quadrant (S,KH,MH): READP this phase's frags (A 4;
//   B 4 when MH==0) -> STG 1 freed region -> [vmcnt(6) @p3/p7] ->
//   sched_barrier -> bar1 -> lgkmcnt(0) -> sched_barrier -> setprio(1) ->
//   16 MFMA -> setprio(0) -> bar2.  Read latency hides under barrier
//   convergence + other waves' MFMA tails (the m201 mechanism).
//   Ledger audited: reads' regions landed (worst: P2 reads prev-P4-staged,
//   covered by prev-P7 vmcnt(6); P6 reads P0-staged, covered by P3); no
//   phase stages a region it ds_reads; every stage is 1 phase after the
//   region's last read with a bar2 between.
//   Swizzle (r3-verified, 0 conflicts): phys kc = kc ^ ((row>>1)&3),
//   both sides.  C/D: col=lane&15, row=(lane>>4)*4+reg (m89).
// ---------------------------------------------------------------------------
#define GK 2048
#define LDS_SLOT 65536
#define LDS_BOFF 32768
#define LDS_KH 16384

__global__ __launch_bounds__(512, 2) void gemm256(const bf16* __restrict__ A,
                                                  const bf16* __restrict__ Bt,
                                                  const float* __restrict__ bias,
                                                  float* __restrict__ C) {
    __shared__ __align__(16) char lds[131072];

    const int tid = threadIdx.x;
    const int wave = tid >> 6, lane = tid & 63;
    const int l15 = lane & 15, kc = lane >> 4;
    const int wm = wave >> 2, wn = wave & 3;

    // T1: bijective XCD swizzle (512 wgs, 512%8==0)
    const int bid = blockIdx.x;
    const int swz = (bid & 7) * 64 + (bid >> 3);
    const int bm = swz >> 3, bn = swz & 7;
    const int mBase = bm * 256, nBase = bn * 256;

    // stage source (pre-swizzled): phys chunk tid -> logical chunk tid^((tid>>3)&3)
    const int c_log = tid ^ ((tid >> 3) & 3);
    const int srow = c_log >> 2, skc = c_log & 3;
    const bf16* gA = A + (size_t)(mBase + srow) * GK + skc * 8;
    const bf16* gB = Bt + (size_t)(nBase + srow) * GK + skc * 8;
    const int stgBase = wave * 1024;

    // read offsets: kcx = kc ^ ((l15>>1)&3)
    const int kcx = kc ^ ((l15 >> 1) & 3);
    const int aoff = wm * 8192 + l15 * 64 + kcx * 16;
    const int boff = LDS_BOFF + wn * 4096 + l15 * 64 + kcx * 16;

    f32x4 acc[8][4];
    #pragma unroll
    for (int i = 0; i < 8; ++i)
        #pragma unroll
        for (int j = 0; j < 4; ++j) acc[i][j] = (f32x4){0.f, 0.f, 0.f, 0.f};

    bf16x8 Af[4], Bf[4];

#define STG(GSRC, LDSC, KT, KH) do {                                        \
    const bf16* _g = (GSRC) + (KT) * 64 + (KH) * 32;                        \
    LOAD_LDS16(_g, lds + (LDSC) + stgBase);                                 \
    LOAD_LDS16(_g + (size_t)128 * GK, lds + (LDSC) + stgBase + 8192);       \
} while (0)

#define READP(SLOT, KH, MH, DOB) do {                                       \
    const int _rb = (SLOT) * LDS_SLOT + (KH) * LDS_KH;                      \
    _Pragma("unroll")                                                       \
    for (int _f = 0; _f < 4; ++_f)                                          \
        Af[_f] = *(const bf16x8*)(lds + _rb + aoff + (MH) * 4096 + _f * 1024); \
    if (DOB) {                                                              \
        _Pragma("unroll")                                                   \
        for (int _f = 0; _f < 4; ++_f)                                      \
            Bf[_f] = *(const bf16x8*)(lds + _rb + boff + _f * 1024);        \
    }                                                                       \
} while (0)

    // prologue: slot0 complete (tile 0), then S1A0,S1B0,S1B1 (tile 1);
    // S1A1 staged by P0.  vmcnt(6): first 8 of 14 loads (slot0) landed.
    STG(gA, 0 * LDS_SLOT + 0, 0, 0);
    STG(gB, 0 * LDS_SLOT + LDS_BOFF + 0, 0, 0);
    STG(gA, 0 * LDS_SLOT + LDS_KH, 0, 1);
    STG(gB, 0 * LDS_SLOT + LDS_BOFF + LDS_KH, 0, 1);
    STG(gA, 1 * LDS_SLOT + 0, 1, 0);
    STG(gB, 1 * LDS_SLOT + LDS_BOFF + 0, 1, 0);
    STG(gB, 1 * LDS_SLOT + LDS_BOFF + LDS_KH, 1, 1);
    asm volatile("s_waitcnt vmcnt(6)");
    __builtin_amdgcn_s_barrier();

    // PH: JIT reads for (S,KH,MH), then stage, then sync+MFMA.
#define PH(S, KH, MH, DOB, SGSRC, SLDS, SKT, SKH, DOVM) do {                \
    READP(S, KH, MH, DOB);                                                  \
    STG(SGSRC, SLDS, SKT, SKH);                                             \
    if (DOVM) asm volatile("s_waitcnt vmcnt(6)");                           \
    __builtin_amdgcn_sched_barrier(0);                                      \
    __builtin_amdgcn_s_barrier();                                           \
    asm volatile("s_waitcnt lgkmcnt(0)");                                   \
    __builtin_amdgcn_sched_barrier(0);                                      \
    __builtin_amdgcn_s_setprio(1);                                          \
    _Pragma("unroll")                                                       \
    for (int _mf = 0; _mf < 4; ++_mf)                                       \
        _Pragma("unroll")                                                   \
        for (int _nf = 0; _nf < 4; ++_nf)                                   \
            acc[(MH) * 4 + _mf][_nf] = __builtin_amdgcn_mfma_f32_16x16x32_bf16( \
                Af[_mf], Bf[_nf], acc[(MH) * 4 + _mf][_nf], 0, 0, 0);       \
    __builtin_amdgcn_s_setprio(0);                                          \
    __builtin_amdgcn_s_barrier();                                           \
} while (0)

    // 32 K-tiles, 2/iter; stage map identical to r3/r4 (HW-verified).
    for (int it = 0; it < 16; ++it) {
        const int t0 = 2 * it;
        const int t1 = (t0 + 1) & 31, t2 = (t0 + 2) & 31, t3 = (t0 + 3) & 31;
        PH(0, 0, 0, 1, gA, 1 * LDS_SLOT + LDS_KH,            t1, 1, 0);
        PH(0, 0, 1, 0, gB, 0 * LDS_SLOT + LDS_BOFF,          t2, 0, 0);
        PH(0, 1, 0, 1, gA, 0 * LDS_SLOT + 0,                 t2, 0, 0);
        PH(0, 1, 1, 0, gB, 0 * LDS_SLOT + LDS_BOFF + LDS_KH, t2, 1, 1);
        PH(1, 0, 0, 1, gA, 0 * LDS_SLOT + LDS_KH,            t2, 1, 0);
        PH(1, 0, 1, 0, gB, 1 * LDS_SLOT + LDS_BOFF,          t3, 0, 0);
        PH(1, 1, 0, 1, gA, 1 * LDS_SLOT + 0,                 t3, 0, 0);
        PH(1, 1, 1, 0, gB, 1 * LDS_SLOT + LDS_BOFF + LDS_KH, t3, 1, 1);
    }

    // epilogue: C/D layout col=lane&15, row=(lane>>4)*4+reg (m89-verified)
    const int cRow0 = mBase + wm * 128 + (lane >> 4) * 4;
    const int cCol0 = nBase + wn * 64 + l15;
    float bv[4];
    #pragma unroll
    for (int nf = 0; nf < 4; ++nf) bv[nf] = bias[cCol0 + nf * 16];
    #pragma unroll
    for (int Mf = 0; Mf < 8; ++Mf)
        #pragma unroll
        for (int nf = 0; nf < 4; ++nf)
            #pragma unroll
            for (int r = 0; r < 4; ++r)
                C[(size_t)(cRow0 + Mf * 16 + r) * GK + cCol0 + nf * 16] =
                    acc[Mf][nf][r] + bv[nf];
#undef PH
#undef READP
#undef STG
}

// ---------------------------------------------------------------------------
// launch
// ---------------------------------------------------------------------------
extern "C" void kernel_launch(void* const* d_in, const int* in_sizes, int n_in,
                              void* d_out, int out_size, void* d_ws, size_t ws_size,
                              hipStream_t stream) {
    const float* x     = (const float*)d_in[0];
    const float* w_in  = (const float*)d_in[1];
    const float* w_out = (const float*)d_in[2];
    const float* b_out = (const float*)d_in[3];
    const float* a_pad = (const float*)d_in[4];
    const float* b_pad = (const float*)d_in[5];
    float* out = (float*)d_out;

    char* ws = (char*)d_ws;
    bf16* x_bf  = (bf16*)ws;                        // 67,108,864 B
    bf16* woutb = (bf16*)(ws + (size_t)67108864);   //  8,388,608 B
    bf16* wint  = (bf16*)(ws + (size_t)75497472);   //  8,388,608 B
    bf16* mcomb = (bf16*)(ws + (size_t)83886080);   //  8,388,608 B  (ws total 92 MB)

    // split-K partials live in d_out (134 MB, fully overwritten by gemm256)
    bf16* part = (bf16*)d_out;                      // 4 x 8 MB

    prep1<<<dim3(6400), dim3(256), 0, stream>>>(w_out, a_pad, b_pad, w_in,
                                                woutb, wint, x, x_bf);
    prep2<<<dim3(1792), dim3(256), 0, stream>>>(woutb, wint, part, x, x_bf);
    addcvt4<<<dim3(NFEAT * BDIM / (256 * 8)), dim3(256), 0, stream>>>(part, mcomb);
    gemm256<<<dim3((BATCH / 256) * (NFEAT / 256)), dim3(512), 0, stream>>>(
        x_bf, mcomb, b_out, out);
}

// Round 10
// 225.991 us; speedup vs baseline: 1.0541x; 1.0089x over previous
//
#include <hip/hip_runtime.h>
#include <hip/hip_bf16.h>

using bf16 = __hip_bfloat16;
using bf16x8 = __attribute__((ext_vector_type(8))) __bf16;
using f32x4 = __attribute__((ext_vector_type(4))) float;

typedef const __attribute__((address_space(1))) void* gas_ptr;
typedef __attribute__((address_space(3))) void* las_ptr;
#define LOAD_LDS16(g, l) \
    __builtin_amdgcn_global_load_lds((gas_ptr)(const void*)(g), (las_ptr)(void*)(l), 16, 0, 0)

#define LOG_DIM 11
#define BDIM 2048
#define NFEAT 2048
#define BATCH 16384

__device__ __forceinline__ void cvt_chunk(const float* __restrict__ x,
                                          bf16* __restrict__ x_bf, int chunk, int tid) {
    #pragma unroll
    for (int it = 0; it < 16; ++it) {
        size_t i = ((size_t)chunk * 16 + it) * 2048 + tid * 8;
        float4 v0 = *(const float4*)(x + i);
        float4 v1 = *(const float4*)(x + i + 4);
        union { bf16 h[8]; int4 v; } u;
        u.h[0] = __float2bfloat16(v0.x); u.h[1] = __float2bfloat16(v0.y);
        u.h[2] = __float2bfloat16(v0.z); u.h[3] = __float2bfloat16(v0.w);
        u.h[4] = __float2bfloat16(v1.x); u.h[5] = __float2bfloat16(v1.y);
        u.h[6] = __float2bfloat16(v1.z); u.h[7] = __float2bfloat16(v1.w);
        *(int4*)(x_bf + i) = u.v;
    }
}

// ---------------------------------------------------------------------------
// prep1: ALL x-cvt [0,1024) || butterfly_wout [1024,3072) || transpose [3072,7168)
//   cvt first (pure BW) so it co-resides with compute-bound butterfly.
// ---------------------------------------------------------------------------
__global__ __launch_bounds__(256) void prep1(const float* __restrict__ w_out,
                                             const float* __restrict__ a_pad,
                                             const float* __restrict__ b_pad,
                                             const float* __restrict__ w_in,
                                             bf16* __restrict__ woutb,
                                             bf16* __restrict__ wint,
                                             const float* __restrict__ x,
                                             bf16* __restrict__ x_bf) {
    __shared__ float v[BDIM];
    __shared__ float tile[32][33];
    const int t = threadIdx.x;
    if (blockIdx.x < 1024) {
        cvt_chunk(x, x_bf, blockIdx.x, t);
    } else if (blockIdx.x < 3072) {
        const int o = blockIdx.x - 1024;
        const float* row = w_out + (size_t)o * BDIM;
        for (int i = t; i < BDIM / 4; i += 256)
            ((float4*)v)[i] = ((const float4*)row)[i];
        __syncthreads();
        for (int l = LOG_DIM - 1; l >= 0; --l) {
            #pragma unroll
            for (int pp = 0; pp < 4; ++pp) {
                int p = t + pp * 256;
                int j = p >> l;
                int s = p & ((1 << l) - 1);
                int i0 = (j << (l + 1)) | s;
                int i1 = i0 + (1 << l);
                float a = a_pad[l * (BDIM / 2) + j];
                float b = b_pad[l * (BDIM / 2) + j];
                float x0 = v[i0], x1 = v[i1];
                v[i0] = a * x0 - b * x1;
                v[i1] = b * x0 + a * x1;
            }
            __syncthreads();
        }
        union { bf16 h[8]; int4 vv; } u;
        #pragma unroll
        for (int j = 0; j < 8; ++j) u.h[j] = __float2bfloat16(v[t * 8 + j]);
        *(int4*)(woutb + (size_t)o * BDIM + t * 8) = u.vv;
    } else {
        const int b = blockIdx.x - 3072;
        const int bx = b & 63, by = b >> 6;
        const int tx = t & 31, ty = t >> 5;
        #pragma unroll
        for (int r = ty; r < 32; r += 8)
            tile[r][tx] = w_in[(size_t)(by * 32 + r) * NFEAT + bx * 32 + tx];
        __syncthreads();
        #pragma unroll
        for (int r = ty; r < 32; r += 8)
            wint[(size_t)(bx * 32 + r) * NFEAT + by * 32 + tx] = __float2bfloat16(tile[tx][r]);
    }
}

// ---------------------------------------------------------------------------
// gemmM_sk: M = WoutB @ W_in^T-layout via the PROVEN gemm256 8-phase
//   structure, splitK=4.  Grid (8,8,4) = 256 blocks = 1/CU, full machine.
//   K=512 per split -> 8 K-tiles -> 4 iterations; wrap &7 (ledger audited:
//   every wrapped stage is 1 phase after that region's last read or dead).
//   bf16 partials -> part[kz].  Same swizzle (r3-verified 0 conflicts).
// ---------------------------------------------------------------------------
#define GK 2048
#define LDS_SLOT 65536
#define LDS_BOFF 32768
#define LDS_KH 16384

__global__ __launch_bounds__(512, 2) void gemmM_sk(const bf16* __restrict__ A,
                                                   const bf16* __restrict__ Bt,
                                                   bf16* __restrict__ part) {
    __shared__ __align__(16) char lds[131072];

    const int tid = threadIdx.x;
    const int wave = tid >> 6, lane = tid & 63;
    const int l15 = lane & 15, kc = lane >> 4;
    const int wm = wave >> 2, wn = wave & 3;

    const int mBase = blockIdx.y * 256, nBase = blockIdx.x * 256;
    const int kz = blockIdx.z;
    bf16* C = part + (size_t)kz * GK * GK;

    const int c_log = tid ^ ((tid >> 3) & 3);
    const int srow = c_log >> 2, skc = c_log & 3;
    const bf16* gA = A + (size_t)(mBase + srow) * GK + kz * 512 + skc * 8;
    const bf16* gB = Bt + (size_t)(nBase + srow) * GK + kz * 512 + skc * 8;
    const int stgBase = wave * 1024;

    const int kcx = kc ^ ((l15 >> 1) & 3);
    const int aoff = wm * 8192 + l15 * 64 + kcx * 16;
    const int boff = LDS_BOFF + wn * 4096 + l15 * 64 + kcx * 16;

    f32x4 acc[8][4];
    #pragma unroll
    for (int i = 0; i < 8; ++i)
        #pragma unroll
        for (int j = 0; j < 4; ++j) acc[i][j] = (f32x4){0.f, 0.f, 0.f, 0.f};

    bf16x8 Af[4], Bf[4];

#define STG(GSRC, LDSC, KT, KH) do {                                        \
    const bf16* _g = (GSRC) + (KT) * 64 + (KH) * 32;                        \
    LOAD_LDS16(_g, lds + (LDSC) + stgBase);                                 \
    LOAD_LDS16(_g + (size_t)128 * GK, lds + (LDSC) + stgBase + 8192);       \
} while (0)

#define READP(SLOT, KH, MH, DOB) do {                                       \
    const int _rb = (SLOT) * LDS_SLOT + (KH) * LDS_KH;                      \
    _Pragma("unroll")                                                       \
    for (int _f = 0; _f < 4; ++_f)                                          \
        Af[_f] = *(const bf16x8*)(lds + _rb + aoff + (MH) * 4096 + _f * 1024); \
    if (DOB) {                                                              \
        _Pragma("unroll")                                                   \
        for (int _f = 0; _f < 4; ++_f)                                      \
            Bf[_f] = *(const bf16x8*)(lds + _rb + boff + _f * 1024);        \
    }                                                                       \
} while (0)

    STG(gA, 0 * LDS_SLOT + 0, 0, 0);
    STG(gB, 0 * LDS_SLOT + LDS_BOFF + 0, 0, 0);
    STG(gA, 0 * LDS_SLOT + LDS_KH, 0, 1);
    STG(gB, 0 * LDS_SLOT + LDS_BOFF + LDS_KH, 0, 1);
    STG(gA, 1 * LDS_SLOT + 0, 1, 0);
    STG(gB, 1 * LDS_SLOT + LDS_BOFF + 0, 1, 0);
    STG(gB, 1 * LDS_SLOT + LDS_BOFF + LDS_KH, 1, 1);
    asm volatile("s_waitcnt vmcnt(6)");
    __builtin_amdgcn_s_barrier();

#define PH(S, KH, MH, DOB, SGSRC, SLDS, SKT, SKH, DOVM) do {                \
    READP(S, KH, MH, DOB);                                                  \
    STG(SGSRC, SLDS, SKT, SKH);                                             \
    if (DOVM) asm volatile("s_waitcnt vmcnt(6)");                           \
    __builtin_amdgcn_sched_barrier(0);                                      \
    __builtin_amdgcn_s_barrier();                                           \
    asm volatile("s_waitcnt lgkmcnt(0)");                                   \
    __builtin_amdgcn_sched_barrier(0);                                      \
    __builtin_amdgcn_s_setprio(1);                                          \
    _Pragma("unroll")                                                       \
    for (int _mf = 0; _mf < 4; ++_mf)                                       \
        _Pragma("unroll")                                                   \
        for (int _nf = 0; _nf < 4; ++_nf)                                   \
            acc[(MH) * 4 + _mf][_nf] = __builtin_amdgcn_mfma_f32_16x16x32_bf16( \
                Af[_mf], Bf[_nf], acc[(MH) * 4 + _mf][_nf], 0, 0, 0);       \
    __builtin_amdgcn_s_setprio(0);                                          \
    __builtin_amdgcn_s_barrier();                                           \
} while (0)

    // 8 K-tiles, 2/iter, wrap &7.
    for (int it = 0; it < 4; ++it) {
        const int t0 = 2 * it;
        const int t1 = (t0 + 1) & 7, t2 = (t0 + 2) & 7, t3 = (t0 + 3) & 7;
        PH(0, 0, 0, 1, gA, 1 * LDS_SLOT + LDS_KH,            t1, 1, 0);
        PH(0, 0, 1, 0, gB, 0 * LDS_SLOT + LDS_BOFF,          t2, 0, 0);
        PH(0, 1, 0, 1, gA, 0 * LDS_SLOT + 0,                 t2, 0, 0);
        PH(0, 1, 1, 0, gB, 0 * LDS_SLOT + LDS_BOFF + LDS_KH, t2, 1, 1);
        PH(1, 0, 0, 1, gA, 0 * LDS_SLOT + LDS_KH,            t2, 1, 0);
        PH(1, 0, 1, 0, gB, 1 * LDS_SLOT + LDS_BOFF,          t3, 0, 0);
        PH(1, 1, 0, 1, gA, 1 * LDS_SLOT + 0,                 t3, 0, 0);
        PH(1, 1, 1, 0, gB, 1 * LDS_SLOT + LDS_BOFF + LDS_KH, t3, 1, 1);
    }

    const int cRow0 = mBase + wm * 128 + (lane >> 4) * 4;
    const int cCol0 = nBase + wn * 64 + l15;
    #pragma unroll
    for (int Mf = 0; Mf < 8; ++Mf)
        #pragma unroll
        for (int nf = 0; nf < 4; ++nf)
            #pragma unroll
            for (int r = 0; r < 4; ++r)
                C[(size_t)(cRow0 + Mf * 16 + r) * GK + cCol0 + nf * 16] =
                    __float2bfloat16(acc[Mf][nf][r]);
#undef PH
#undef READP
#undef STG
}

// ---------------------------------------------------------------------------
// add four bf16 partials -> bf16
// ---------------------------------------------------------------------------
__global__ __launch_bounds__(256) void addcvt4(const bf16* __restrict__ p,
                                               bf16* __restrict__ out) {
    size_t i = ((size_t)blockIdx.x * 256 + threadIdx.x) * 8;
    constexpr size_t STRIDE = (size_t)2048 * 2048;
    float s[8];
    #pragma unroll
    for (int j = 0; j < 8; ++j) s[j] = 0.f;
    #pragma unroll
    for (int z = 0; z < 4; ++z) {
        union { bf16 h[8]; int4 v; } a;
        a.v = *(const int4*)(p + z * STRIDE + i);
        #pragma unroll
        for (int j = 0; j < 8; ++j) s[j] += __bfloat162float(a.h[j]);
    }
    union { bf16 h[8]; int4 v; } o;
    #pragma unroll
    for (int j = 0; j < 8; ++j) o.h[j] = __float2bfloat16(s[j]);
    *(int4*)(out + i) = o.v;
}

// ---------------------------------------------------------------------------
// Main GEMM (r9: 16x16 MFMA, r3-verified swizzle, JIT-read phase order).
//   141 µs / 42% MfmaUtil / 0 conflicts — best-known for this shape.
// ---------------------------------------------------------------------------
__global__ __launch_bounds__(512, 2) void gemm256(const bf16* __restrict__ A,
                                                  const bf16* __restrict__ Bt,
                                                  const float* __restrict__ bias,
                                                  float* __restrict__ C) {
    __shared__ __align__(16) char lds[131072];

    const int tid = threadIdx.x;
    const int wave = tid >> 6, lane = tid & 63;
    const int l15 = lane & 15, kc = lane >> 4;
    const int wm = wave >> 2, wn = wave & 3;

    const int bid = blockIdx.x;
    const int swz = (bid & 7) * 64 + (bid >> 3);
    const int bm = swz >> 3, bn = swz & 7;
    const int mBase = bm * 256, nBase = bn * 256;

    const int c_log = tid ^ ((tid >> 3) & 3);
    const int srow = c_log >> 2, skc = c_log & 3;
    const bf16* gA = A + (size_t)(mBase + srow) * GK + skc * 8;
    const bf16* gB = Bt + (size_t)(nBase + srow) * GK + skc * 8;
    const int stgBase = wave * 1024;

    const int kcx = kc ^ ((l15 >> 1) & 3);
    const int aoff = wm * 8192 + l15 * 64 + kcx * 16;
    const int boff = LDS_BOFF + wn * 4096 + l15 * 64 + kcx * 16;

    f32x4 acc[8][4];
    #pragma unroll
    for (int i = 0; i < 8; ++i)
        #pragma unroll
        for (int j = 0; j < 4; ++j) acc[i][j] = (f32x4){0.f, 0.f, 0.f, 0.f};

    bf16x8 Af[4], Bf[4];

#define STG(GSRC, LDSC, KT, KH) do {                                        \
    const bf16* _g = (GSRC) + (KT) * 64 + (KH) * 32;                        \
    LOAD_LDS16(_g, lds + (LDSC) + stgBase);                                 \
    LOAD_LDS16(_g + (size_t)128 * GK, lds + (LDSC) + stgBase + 8192);       \
} while (0)

#define READP(SLOT, KH, MH, DOB) do {                                       \
    const int _rb = (SLOT) * LDS_SLOT + (KH) * LDS_KH;                      \
    _Pragma("unroll")                                                       \
    for (int _f = 0; _f < 4; ++_f)                                          \
        Af[_f] = *(const bf16x8*)(lds + _rb + aoff + (MH) * 4096 + _f * 1024); \
    if (DOB) {                                                              \
        _Pragma("unroll")                                                   \
        for (int _f = 0; _f < 4; ++_f)                                      \
            Bf[_f] = *(const bf16x8*)(lds + _rb + boff + _f * 1024);        \
    }                                                                       \
} while (0)

    STG(gA, 0 * LDS_SLOT + 0, 0, 0);
    STG(gB, 0 * LDS_SLOT + LDS_BOFF + 0, 0, 0);
    STG(gA, 0 * LDS_SLOT + LDS_KH, 0, 1);
    STG(gB, 0 * LDS_SLOT + LDS_BOFF + LDS_KH, 0, 1);
    STG(gA, 1 * LDS_SLOT + 0, 1, 0);
    STG(gB, 1 * LDS_SLOT + LDS_BOFF + 0, 1, 0);
    STG(gB, 1 * LDS_SLOT + LDS_BOFF + LDS_KH, 1, 1);
    asm volatile("s_waitcnt vmcnt(6)");
    __builtin_amdgcn_s_barrier();

#define PH(S, KH, MH, DOB, SGSRC, SLDS, SKT, SKH, DOVM) do {                \
    READP(S, KH, MH, DOB);                                                  \
    STG(SGSRC, SLDS, SKT, SKH);                                             \
    if (DOVM) asm volatile("s_waitcnt vmcnt(6)");                           \
    __builtin_amdgcn_sched_barrier(0);                                      \
    __builtin_amdgcn_s_barrier();                                           \
    asm volatile("s_waitcnt lgkmcnt(0)");                                   \
    __builtin_amdgcn_sched_barrier(0);                                      \
    __builtin_amdgcn_s_setprio(1);                                          \
    _Pragma("unroll")                                                       \
    for (int _mf = 0; _mf < 4; ++_mf)                                       \
        _Pragma("unroll")                                                   \
        for (int _nf = 0; _nf < 4; ++_nf)                                   \
            acc[(MH) * 4 + _mf][_nf] = __builtin_amdgcn_mfma_f32_16x16x32_bf16( \
                Af[_mf], Bf[_nf], acc[(MH) * 4 + _mf][_nf], 0, 0, 0);       \
    __builtin_amdgcn_s_setprio(0);                                          \
    __builtin_amdgcn_s_barrier();                                           \
} while (0)

    for (int it = 0; it < 16; ++it) {
        const int t0 = 2 * it;
        const int t1 = (t0 + 1) & 31, t2 = (t0 + 2) & 31, t3 = (t0 + 3) & 31;
        PH(0, 0, 0, 1, gA, 1 * LDS_SLOT + LDS_KH,            t1, 1, 0);
        PH(0, 0, 1, 0, gB, 0 * LDS_SLOT + LDS_BOFF,          t2, 0, 0);
        PH(0, 1, 0, 1, gA, 0 * LDS_SLOT + 0,                 t2, 0, 0);
        PH(0, 1, 1, 0, gB, 0 * LDS_SLOT + LDS_BOFF + LDS_KH, t2, 1, 1);
        PH(1, 0, 0, 1, gA, 0 * LDS_SLOT + LDS_KH,            t2, 1, 0);
        PH(1, 0, 1, 0, gB, 1 * LDS_SLOT + LDS_BOFF,          t3, 0, 0);
        PH(1, 1, 0, 1, gA, 1 * LDS_SLOT + 0,                 t3, 0, 0);
        PH(1, 1, 1, 0, gB, 1 * LDS_SLOT + LDS_BOFF + LDS_KH, t3, 1, 1);
    }

    const int cRow0 = mBase + wm * 128 + (lane >> 4) * 4;
    const int cCol0 = nBase + wn * 64 + l15;
    float bv[4];
    #pragma unroll
    for (int nf = 0; nf < 4; ++nf) bv[nf] = bias[cCol0 + nf * 16];
    #pragma unroll
    for (int Mf = 0; Mf < 8; ++Mf)
        #pragma unroll
        for (int nf = 0; nf < 4; ++nf)
            #pragma unroll
            for (int r = 0; r < 4; ++r)
                C[(size_t)(cRow0 + Mf * 16 + r) * GK + cCol0 + nf * 16] =
                    acc[Mf][nf][r] + bv[nf];
#undef PH
#undef READP
#undef STG
}

// ---------------------------------------------------------------------------
// launch
// ---------------------------------------------------------------------------
extern "C" void kernel_launch(void* const* d_in, const int* in_sizes, int n_in,
                              void* d_out, int out_size, void* d_ws, size_t ws_size,
                              hipStream_t stream) {
    const float* x     = (const float*)d_in[0];
    const float* w_in  = (const float*)d_in[1];
    const float* w_out = (const float*)d_in[2];
    const float* b_out = (const float*)d_in[3];
    const float* a_pad = (const float*)d_in[4];
    const float* b_pad = (const float*)d_in[5];
    float* out = (float*)d_out;

    char* ws = (char*)d_ws;
    bf16* x_bf  = (bf16*)ws;                        // 67,108,864 B
    bf16* woutb = (bf16*)(ws + (size_t)67108864);   //  8,388,608 B
    bf16* wint  = (bf16*)(ws + (size_t)75497472);   //  8,388,608 B
    bf16* mcomb = (bf16*)(ws + (size_t)83886080);   //  8,388,608 B  (ws total 92 MB)

    // split-K partials live in d_out (134 MB, fully overwritten by gemm256)
    bf16* part = (bf16*)d_out;                      // 4 x 8 MB

    // prep1: ALL x-cvt || butterfly(W_out) || transpose(W_in)
    prep1<<<dim3(7168), dim3(256), 0, stream>>>(w_out, a_pad, b_pad, w_in,
                                                woutb, wint, x, x_bf);
    // M = (W_out·B) @ W_in: proven 8-phase 256² structure, splitK=4, 1 blk/CU
    gemmM_sk<<<dim3(8, 8, 4), dim3(512), 0, stream>>>(woutb, wint, part);
    addcvt4<<<dim3(NFEAT * BDIM / (256 * 8)), dim3(256), 0, stream>>>(part, mcomb);
    // out = x @ M^T + b
    gemm256<<<dim3((BATCH / 256) * (NFEAT / 256)), dim3(512), 0, stream>>>(
        x_bf, mcomb, b_out, out);
}